// Round 8
// baseline (2368.906 us; speedup 1.0000x reference)
//
#include <hip/hip_runtime.h>

#define M 256     // rows of S (n_hos*n_types)
#define N 4096    // cols of S (n_structs)
#define NIT 200   // PDHG iterations
#define PIT 30    // power iterations

// dummy byte-offsets (float2 slots): y_s[256], z_s[4096]
#define YDUMMY (256*8)
#define ZDUMMY (4096*8)

// ---------------- counts ----------------
__global__ void k_colcnt(const float* __restrict__ S, int* __restrict__ col_cnt){
  int j = blockIdx.x*256 + threadIdx.x;
  int c = 0;
  for (int i = 0; i < M; ++i) c += (S[i*N + j] != 0.0f) ? 1 : 0;
  col_cnt[j] = c;
}

__global__ void k_rowcnt(const float* __restrict__ S, int* __restrict__ row_cnt){
  int wid = blockIdx.x*(blockDim.x>>6) + (threadIdx.x>>6);
  int l = threadIdx.x & 63;
  if (wid >= M) return;
  int cnt = 0;
  for (int jc = 0; jc < N/64; ++jc){
    float v = S[wid*N + jc*64 + l];
    unsigned long long mask = __ballot(v != 0.0f);
    cnt += __popcll(mask);
  }
  if (l == 0) row_cnt[wid] = cnt;
}

// ---------------- deterministic rank sort by (cnt, index) ----------------
__global__ void k_sortcol(const int* __restrict__ col_cnt,
                          int* __restrict__ col_perm, int* __restrict__ col_rank){
  __shared__ int cs[N];
  int t0 = threadIdx.x;
  for (int t = 0; t < N/256; ++t) cs[t0 + 256*t] = col_cnt[t0 + 256*t];
  __syncthreads();
  int j = blockIdx.x*256 + t0;
  int cj = cs[j];
  int rank = 0;
  #pragma unroll 4
  for (int jj = 0; jj < N; ++jj){
    int c = cs[jj];
    rank += ((c < cj) || (c == cj && jj < j)) ? 1 : 0;
  }
  col_perm[rank] = j;
  col_rank[j] = rank;
}

__global__ void k_sortrow(const int* __restrict__ row_cnt,
                          int* __restrict__ row_perm, int* __restrict__ row_rank){
  int i = threadIdx.x;
  int ci = row_cnt[i];
  int rank = 0;
  for (int ii = 0; ii < M; ++ii){
    int c = row_cnt[ii];
    rank += ((c < ci) || (c == ci && ii < i)) ? 1 : 0;
  }
  row_perm[rank] = i;
  row_rank[i] = rank;
}

// ---------------- wave-trip counts + base offsets (TRIP units) ----------
__global__ void k_trips(const int* __restrict__ col_cnt, const int* __restrict__ col_perm,
                        const int* __restrict__ row_cnt, const int* __restrict__ row_perm,
                        int* __restrict__ pT4, int* __restrict__ pB4,
                        int* __restrict__ dT4, int* __restrict__ dB4){
  int tid = threadIdx.x;
  if (tid < 64){
    int k = tid >> 4, w = tid & 15;
    int mx = 0;
    for (int l = 0; l < 64; ++l){
      int s = 64*w + l + 1024*k;
      int c = col_cnt[col_perm[s]];
      mx = max(mx, c);
    }
    pT4[tid] = min((mx + 3) >> 2, 16);
  } else if (tid < 80){
    int w = tid - 64;
    int mx = 0;
    for (int l = 0; l < 64; ++l){
      int t = w*64 + l;
      int r = t >> 2, q = t & 3;
      int len = row_cnt[row_perm[r]];
      int qs = (len*q) >> 2, qe = (len*(q+1)) >> 2;
      mx = max(mx, qe - qs);
    }
    dT4[w] = min((mx + 3) >> 2, 80);
  }
  __syncthreads();
  if (tid == 0){
    int acc = 0;
    for (int i = 0; i < 64; ++i){ pB4[i] = acc; acc += pT4[i]; }
    acc = 0;
    for (int i = 0; i < 16; ++i){ dB4[i] = acc; acc += dT4[i]; }
  }
}

// ============ bank-balanced greedy scheduling (fill-time) ===============
// Class of a float2 slot s = s & 15 (owns banks 2c,2c+1). For each gather
// instruction (slot t, 64 lanes), schedule picks so <=4 lanes/class:
// 4 sub-rounds of 16 lanes; pick argmin (cnt[c]<<4 | (c-l)&15) among the
// lane's remaining classes; idle if slack and best class full; counters
// replicated in regs, updated via ballots. Deterministic.

// ---------------- primal fill: one 64-thread block per group kw ---------
__global__ __launch_bounds__(64) void k_fillp(
    const float* __restrict__ S, const int* __restrict__ col_perm,
    const int* __restrict__ pT4, const int* __restrict__ pB4,
    unsigned short* __restrict__ pstream)
{
  const int b = blockIdx.x;            // group kw: w = b&15, k = b>>4
  const int l = threadIdx.x;
  const int base = pB4[b], cap = pT4[b]*4;
  const int j = col_perm[64*(b & 15) + l + 1024*(b >> 4)];

  __shared__ unsigned short msk[64][16];   // per lane/class: bitmask of m (i = c+16m)
  unsigned long long remA = 0, remB = 0;   // 8-bit per-class counts
  int remT = 0;
  #pragma unroll
  for (int c = 0; c < 16; ++c) msk[l][c] = 0;
  for (int i = 0; i < M; ++i){
    if (S[(size_t)i*N + j] != 0.0f && remT < cap){
      int c = i & 15, m = i >> 4;
      msk[l][c] |= (unsigned short)(1u << m);
      if (c < 8) remA += 1ull << (c*8); else remB += 1ull << ((c-8)*8);
      ++remT;
    }
  }

  unsigned long long cntA = 0, cntB = 0;
  for (int t = 0; t < cap; ++t){
    int myround = ((l >> 4) + t) & 3;
    int pick = 16;
    for (int r = 0; r < 4; ++r){
      if (r == myround && remT > 0){
        bool forced = (remT >= cap - t);
        int bestc = -1, bestkey = 1 << 30, bestcnt = 0;
        #pragma unroll
        for (int c = 0; c < 16; ++c){
          int rc = (int)(((c < 8) ? (remA >> (c*8)) : (remB >> ((c-8)*8))) & 0xff);
          if (rc){
            int cc = (int)(((c < 8) ? (cntA >> (c*8)) : (cntB >> ((c-8)*8))) & 0xff);
            int key = (cc << 4) | ((c - l) & 15);
            if (key < bestkey){ bestkey = key; bestc = c; bestcnt = cc; }
          }
        }
        if (bestc >= 0 && (forced || bestcnt < 4)) pick = bestc;
      }
      int np = (r == myround) ? pick : 16;
      #pragma unroll
      for (int c = 0; c < 16; ++c){
        int add = (int)__popcll(__ballot(np == c));
        if (add){
          if (c < 8) cntA += (unsigned long long)add << (c*8);
          else       cntB += (unsigned long long)add << ((c-8)*8);
        }
      }
    }
    unsigned short off;
    if (pick < 16){
      unsigned short mm = msk[l][pick];
      int m = __builtin_ctz((unsigned)mm);
      msk[l][pick] = (unsigned short)(mm & (mm - 1));
      if (pick < 8) remA -= 1ull << (pick*8); else remB -= 1ull << ((pick-8)*8);
      --remT;
      off = (unsigned short)((pick + 16*m) * 8);
    } else {
      off = (unsigned short)YDUMMY;
    }
    pstream[((base + (t>>2))*64 + l)*4 + (t&3)] = off;
  }
}

// ---------------- dual fill: one 64-thread block per consumer wave ------
__global__ __launch_bounds__(64) void k_filld(
    const float* __restrict__ S,
    const int* __restrict__ row_cnt, const int* __restrict__ row_perm,
    const int* __restrict__ dT4, const int* __restrict__ dB4,
    unsigned short* __restrict__ dstream)
{
  const int w = blockIdx.x;            // consumer wave 0..15
  const int l = threadIdx.x;
  const int base = dB4[w], cap = dT4[w]*4;
  const int rr = w*16 + (l >> 2);      // sorted row slot
  const int q  = l & 3;
  const int i  = row_perm[rr];
  const int len = row_cnt[i];
  const int qs = (len*q) >> 2, qe = (len*(q+1)) >> 2;

  __shared__ unsigned long long msk[64][16][4];  // 32 KB: per lane/class m-bitmask (j = c+16m)
  unsigned long long remA = 0, remB = 0;
  int remT = 0;
  #pragma unroll
  for (int c = 0; c < 16; ++c)
    for (int wd = 0; wd < 4; ++wd) msk[l][c][wd] = 0ull;

  int rho = 0;
  for (int j = 0; j < N; ++j){
    if (S[(size_t)i*N + j] != 0.0f){
      if (rho >= qs && rho < qe && remT < cap){
        int c = j & 15, m = j >> 4;
        msk[l][c][m >> 6] |= 1ull << (m & 63);
        if (c < 8) remA += 1ull << (c*8); else remB += 1ull << ((c-8)*8);
        ++remT;
      }
      ++rho;
    }
  }

  unsigned long long cntA = 0, cntB = 0;
  for (int t = 0; t < cap; ++t){
    int myround = ((l >> 4) + t) & 3;
    int pick = 16;
    for (int r = 0; r < 4; ++r){
      if (r == myround && remT > 0){
        bool forced = (remT >= cap - t);
        int bestc = -1, bestkey = 1 << 30, bestcnt = 0;
        #pragma unroll
        for (int c = 0; c < 16; ++c){
          int rc = (int)(((c < 8) ? (remA >> (c*8)) : (remB >> ((c-8)*8))) & 0xff);
          if (rc){
            int cc = (int)(((c < 8) ? (cntA >> (c*8)) : (cntB >> ((c-8)*8))) & 0xff);
            int key = (cc << 4) | ((c - l) & 15);
            if (key < bestkey){ bestkey = key; bestc = c; bestcnt = cc; }
          }
        }
        if (bestc >= 0 && (forced || bestcnt < 4)) pick = bestc;
      }
      int np = (r == myround) ? pick : 16;
      #pragma unroll
      for (int c = 0; c < 16; ++c){
        int add = (int)__popcll(__ballot(np == c));
        if (add){
          if (c < 8) cntA += (unsigned long long)add << (c*8);
          else       cntB += (unsigned long long)add << ((c-8)*8);
        }
      }
    }
    unsigned short off;
    if (pick < 16){
      int wd = 0;
      unsigned long long mm = msk[l][pick][0];
      if (!mm){ mm = msk[l][pick][1]; wd = 1; }
      if (!mm){ mm = msk[l][pick][2]; wd = 2; }
      if (!mm){ mm = msk[l][pick][3]; wd = 3; }
      int bit = __builtin_ctzll(mm);
      msk[l][pick][wd] = mm & (mm - 1);
      if (pick < 8) remA -= 1ull << (pick*8); else remB -= 1ull << ((pick-8)*8);
      --remT;
      int j = pick + 16*(wd*64 + bit);
      off = (unsigned short)(j * 8);
    } else {
      off = (unsigned short)ZDUMMY;
    }
    dstream[((base + (t>>2))*64 + l)*4 + (t&3)] = off;
  }
}

// ---------------- power iteration (no per-step normalize) ---------------
__global__ __launch_bounds__(1024) void k_power(
    const ushort4* __restrict__ pstream, const ushort4* __restrict__ dstream,
    const int* __restrict__ col_perm, const int* __restrict__ row_perm,
    const int* __restrict__ pT4, const int* __restrict__ pB4,
    const int* __restrict__ dT4, const int* __restrict__ dB4,
    float* __restrict__ tauw)
{
  __shared__ float2 v_s[N+8];
  __shared__ float2 u_s[M+8];
  __shared__ float2 red2[1024];
  const int tid = threadIdx.x, w = tid >> 6, l = tid & 63;

  int cj[4], pb[4], pt[4];
  float tl[4];
  #pragma unroll
  for (int k = 0; k < 4; ++k){
    int kw = k*16 + w;
    pb[k] = pB4[kw]; pt[k] = pT4[kw];
    cj[k] = col_perm[tid + 1024*k];
    v_s[cj[k]] = make_float2(1.0f, 0.0f);
    tl[k] = 0.0f;
  }
  const int r = tid >> 2, q = tid & 3;
  const int rid = row_perm[r];
  const int db = dB4[w], dt = dT4[w];
  if (tid < 8){ v_s[N+tid] = make_float2(0,0); u_s[M+tid] = make_float2(0,0); }
  __syncthreads();

  const char* vb = (const char*)v_s;
  const char* ub = (const char*)u_s;

  for (int it = 0; it < PIT; ++it){
    float a = 0.0f;
    for (int c = 0; c < dt; ++c){
      ushort4 ix = dstream[(db + c)*64 + l];
      a += ((const float2*)(vb + ix.x))->x + ((const float2*)(vb + ix.y))->x
         + ((const float2*)(vb + ix.z))->x + ((const float2*)(vb + ix.w))->x;
    }
    a += __shfl_xor(a, 1);
    a += __shfl_xor(a, 2);
    if (q == 0) u_s[rid] = make_float2(a, 0.0f);
    __syncthreads();
    #pragma unroll
    for (int k = 0; k < 4; ++k){
      float a2 = 0.0f;
      for (int c = 0; c < pt[k]; ++c){
        ushort4 ix = pstream[(pb[k] + c)*64 + l];
        a2 += ((const float2*)(ub + ix.x))->x + ((const float2*)(ub + ix.y))->x
            + ((const float2*)(ub + ix.z))->x + ((const float2*)(ub + ix.w))->x;
      }
      tl[k] = a2 * (1.0f/1024.0f);
      v_s[cj[k]] = make_float2(tl[k], 0.0f);
    }
    __syncthreads();
  }

  float pv = 0.0f;
  #pragma unroll
  for (int k = 0; k < 4; ++k) pv += tl[k]*tl[k];
  float a = 0.0f;
  for (int c = 0; c < dt; ++c){
    ushort4 ix = dstream[(db + c)*64 + l];
    a += ((const float2*)(vb + ix.x))->x + ((const float2*)(vb + ix.y))->x
       + ((const float2*)(vb + ix.z))->x + ((const float2*)(vb + ix.w))->x;
  }
  a += __shfl_xor(a, 1);
  a += __shfl_xor(a, 2);
  float fsq = (q == 0) ? a*a : 0.0f;
  red2[tid] = make_float2(pv, fsq);
  __syncthreads();
  for (int sd = 512; sd > 0; sd >>= 1){
    if (tid < sd){
      red2[tid].x += red2[tid+sd].x;
      red2[tid].y += red2[tid+sd].y;
    }
    __syncthreads();
  }
  if (tid == 0) tauw[0] = 0.9f * sqrtf(red2[0].x / red2[0].y);
}

// ---------------- persistent PDHG: one block per 2 batches --------------
__global__ __launch_bounds__(1024) void k_main(
    const float* __restrict__ X,
    const ushort4* __restrict__ pstream, const ushort4* __restrict__ dstream,
    const int* __restrict__ col_perm, const int* __restrict__ row_perm,
    const int* __restrict__ pT4, const int* __restrict__ pB4,
    const int* __restrict__ dT4, const int* __restrict__ dB4,
    const float* __restrict__ tauw, float* __restrict__ out)
{
  __shared__ float2 z_s[N+8];
  __shared__ float2 y_s[M+8];
  const int tid = threadIdx.x, w = tid >> 6, l = tid & 63;
  const int b0 = blockIdx.x * 2;
  const float tau = tauw[0];
  const float sigma = tau;

  int cj[4], pb[4], pt[4];
  float2 x[4];
  #pragma unroll
  for (int k = 0; k < 4; ++k){
    int kw = k*16 + w;
    pb[k] = pB4[kw]; pt[k] = pT4[kw];
    cj[k] = col_perm[tid + 1024*k];
    x[k] = make_float2(0.0f, 0.0f);
  }
  const int r = tid >> 2, q = tid & 3;
  const int rid = row_perm[r];
  const int db = dB4[w], dt = dT4[w];
  float2 bi = make_float2(0,0), yv = make_float2(0,0);
  if (q == 0){
    bi.x = X[b0*M + rid];
    bi.y = X[(b0+1)*M + rid];
    y_s[rid] = make_float2(0,0);
  }
  if (tid < 8){ y_s[M+tid] = make_float2(0,0); z_s[N+tid] = make_float2(0,0); }
  __syncthreads();

  const char* yb = (const char*)y_s;
  const char* zb = (const char*)z_s;

  for (int it = 0; it < NIT; ++it){
    const bool last = (it == NIT-1);
    // primal: x+ = max(x + tau*(1 - y S), 0); z = 2 x+ - x
    #pragma unroll
    for (int k = 0; k < 4; ++k){
      float ax = 0.0f, ay = 0.0f;
      for (int c = 0; c < pt[k]; ++c){
        ushort4 ix = pstream[(pb[k] + c)*64 + l];
        float2 a0 = *(const float2*)(yb + ix.x);
        float2 a1 = *(const float2*)(yb + ix.y);
        float2 a2 = *(const float2*)(yb + ix.z);
        float2 a3 = *(const float2*)(yb + ix.w);
        ax += (a0.x + a1.x) + (a2.x + a3.x);
        ay += (a0.y + a1.y) + (a2.y + a3.y);
      }
      float2 xo = x[k];
      float xnx = fmaxf(xo.x + tau*(1.0f - ax), 0.0f);
      float xny = fmaxf(xo.y + tau*(1.0f - ay), 0.0f);
      if (!last) z_s[cj[k]] = make_float2(2.0f*xnx - xo.x, 2.0f*xny - xo.y);
      x[k] = make_float2(xnx, xny);
    }
    if (last) break;
    __syncthreads();
    // dual: quarter-row gathers + in-wave reduce across q
    float ax = 0.0f, ay = 0.0f;
    for (int c = 0; c < dt; ++c){
      ushort4 ix = dstream[(db + c)*64 + l];
      float2 a0 = *(const float2*)(zb + ix.x);
      float2 a1 = *(const float2*)(zb + ix.y);
      float2 a2 = *(const float2*)(zb + ix.z);
      float2 a3 = *(const float2*)(zb + ix.w);
      ax += (a0.x + a1.x) + (a2.x + a3.x);
      ay += (a0.y + a1.y) + (a2.y + a3.y);
    }
    ax += __shfl_xor(ax, 1);  ay += __shfl_xor(ay, 1);
    ax += __shfl_xor(ax, 2);  ay += __shfl_xor(ay, 2);
    if (q == 0){
      yv.x = fmaxf(yv.x + sigma*(ax - bi.x), 0.0f);
      yv.y = fmaxf(yv.y + sigma*(ay - bi.y), 0.0f);
      y_s[rid] = yv;
    }
    __syncthreads();
  }

  #pragma unroll
  for (int k = 0; k < 4; ++k){
    out[(size_t)b0*N + cj[k]]     = x[k].x;
    out[(size_t)(b0+1)*N + cj[k]] = x[k].y;
  }
}

// ---------------- launcher ----------------
extern "C" void kernel_launch(void* const* d_in, const int* in_sizes, int n_in,
                              void* d_out, int out_size, void* d_ws, size_t ws_size,
                              hipStream_t stream)
{
  const float* X = (const float*)d_in[0];   // [B, 16, 16] -> b
  const float* S = (const float*)d_in[1];   // [M, N]
  float* out = (float*)d_out;               // [B, N] fp32
  const int B = in_sizes[0] / M;            // 512

  char* p = (char*)d_ws;
  auto alloc = [&](size_t bytes)->char*{
    char* q = p; p += (bytes + 255) & ~size_t(255); return q;
  };
  int* col_cnt  = (int*)alloc(N*sizeof(int));
  int* col_perm = (int*)alloc(N*sizeof(int));
  int* col_rank = (int*)alloc(N*sizeof(int));
  int* row_cnt  = (int*)alloc(M*sizeof(int));
  int* row_perm = (int*)alloc(M*sizeof(int));
  int* row_rank = (int*)alloc(M*sizeof(int));
  int* pT4      = (int*)alloc(64*sizeof(int));
  int* pB4      = (int*)alloc(64*sizeof(int));
  int* dT4      = (int*)alloc(16*sizeof(int));
  int* dB4      = (int*)alloc(16*sizeof(int));
  float* tauw   = (float*)alloc(256);
  unsigned short* pstream = (unsigned short*)alloc(65536ull*8);
  unsigned short* dstream = (unsigned short*)alloc(81920ull*8);

  k_colcnt <<<N/256, 256, 0, stream>>>(S, col_cnt);
  k_rowcnt <<<16, 1024, 0, stream>>>(S, row_cnt);
  k_sortcol<<<N/256, 256, 0, stream>>>(col_cnt, col_perm, col_rank);
  k_sortrow<<<1, M, 0, stream>>>(row_cnt, row_perm, row_rank);
  k_trips  <<<1, 256, 0, stream>>>(col_cnt, col_perm, row_cnt, row_perm, pT4, pB4, dT4, dB4);
  k_fillp  <<<64, 64, 0, stream>>>(S, col_perm, pT4, pB4, pstream);
  k_filld  <<<16, 64, 0, stream>>>(S, row_cnt, row_perm, dT4, dB4, dstream);
  k_power  <<<1, 1024, 0, stream>>>((const ushort4*)pstream, (const ushort4*)dstream,
                                    col_perm, row_perm, pT4, pB4, dT4, dB4, tauw);
  k_main   <<<B/2, 1024, 0, stream>>>(X, (const ushort4*)pstream, (const ushort4*)dstream,
                                      col_perm, row_perm, pT4, pB4, dT4, dB4, tauw, out);
}